// Round 7
// baseline (244.928 us; speedup 1.0000x reference)
//
#include <hip/hip_runtime.h>

#define HH 512
#define WW 512
#define HW (HH*WW)
#define EPV 1e-20f

// Box window for center (y,x): rows y-3..y+4, cols x-3..x+4, zero-padded.
// Streaming cascade per wave (verified absmax 0.0078 in R5/R6):
//   r = y0-7+t : raw row loaded; ha = win8(raw); VA(ring8) = box rows c-3..c+4
//   t>=8      : c = r-4; acv = (raw(c) - VA/64) [0 outside image]
//               hii = win8(acv^2); VSII(ring8) = box rows y-3..y+4
//               hp_j = win8(acv*bcv_j); VS_j(ring8)
//   t>=15     : y = c-4; emit.

__device__ __forceinline__ float bpf(int addr, float v) {
    return __int_as_float(__builtin_amdgcn_ds_bpermute(addr, __float_as_int(v)));
}

// h(l) = sum_{d=1..8} v(l+d); valid for lanes l <= 55 (wave64).
__device__ __forceinline__ float win8(float v, int a1, int a2, int a4) {
    float t = v + bpf(a1, v);
    t = t + bpf(a2, t);
    t = t + bpf(a4, t);
    return bpf(a1, t);
}

// ---------------- prep_b: 4 label images per wave -> interleaved bc4, sjj4 --
// One wave per (b, 48-col strip, 16-row seg). Writes:
//   bc4 [((b*512 + c)*512 + x)*4 + j]  centered label values
//   sjj4[((b*512 + y)*512 + x)*4 + j]  max(box(bc^2), EPV)
__global__ __launch_bounds__(64) void prep_b(
    const float* __restrict__ labs,
    float* __restrict__ bc4, float* __restrict__ sjj4)
{
    const int l  = threadIdx.x;
    const int x0 = 48 * blockIdx.x;
    const int y0 = 16 * blockIdx.y;
    const int b  = blockIdx.z;

    const float* src[4];
    #pragma unroll
    for (int j = 0; j < 4; ++j) src[j] = labs + (b * 4 + j) * HW;

    const int   gin  = x0 - 4 + l;
    const int   ginc = min(max(gin, 0), WW - 1);
    const float minA = (gin >= 0 && gin < WW) ? 1.f : 0.f;
    const int   a1 = ((l + 1) & 63) << 2, a2 = ((l + 2) & 63) << 2, a4 = ((l + 4) & 63) << 2;

    const bool st_c = (l >= 4 && l < 52 && gin < WW);
    const int  gout = x0 + l;
    const bool st_s = (l < 48 && gout < WW);

    float araw[4][4], ha8[4][8], hii8[4][8], VA[4], VSII[4];
    #pragma unroll
    for (int j = 0; j < 4; ++j) {
        VA[j] = 0.f; VSII[j] = 0.f;
        #pragma unroll
        for (int k = 0; k < 4; ++k) araw[j][k] = 0.f;
        #pragma unroll
        for (int k = 0; k < 8; ++k) { ha8[j][k] = 0.f; hii8[j][k] = 0.f; }
    }

    auto step = [&](int t, int k) {
        const int r = y0 - 7 + t;
        const bool rok = (r >= 0 && r < HH);
        float av[4];
        #pragma unroll
        for (int j = 0; j < 4; ++j)
            av[j] = rok ? src[j][r * WW + ginc] * minA : 0.f;
        float acv[4];
        #pragma unroll
        for (int j = 0; j < 4; ++j) {
            float han = win8(av[j], a1, a2, a4);
            VA[j] += han - ha8[j][k]; ha8[j][k] = han;
            float aold = araw[j][k & 3];
            araw[j][k & 3] = av[j];
            const int c = r - 4;
            acv[j] = (c >= 0 && c < HH) ? (aold - VA[j] * (1.f / 64.f)) * minA : 0.f;
        }
        if (t >= 8) {
            const int c = r - 4;
            if (c >= y0 && c < y0 + 16 && st_c)
                *(float4*)&bc4[(((c)*WW + gin) + b * HW) * 4] =
                    make_float4(acv[0], acv[1], acv[2], acv[3]);
            float sj[4];
            #pragma unroll
            for (int j = 0; j < 4; ++j) {
                float hin = win8(acv[j] * acv[j], a1, a2, a4);
                VSII[j] += hin - hii8[j][k]; hii8[j][k] = hin;
                sj[j] = fmaxf(VSII[j], EPV);
            }
            if (t >= 15) {
                const int y = c - 4;
                if (st_s)
                    *(float4*)&sjj4[(((y)*WW + gout) + b * HW) * 4] =
                        make_float4(sj[0], sj[1], sj[2], sj[3]);
            }
        }
    };

    for (int g = 0; g < 3; ++g) {
        #pragma unroll
        for (int k = 0; k < 8; ++k) step(g * 8 + k, k);
    }
    #pragma unroll
    for (int k = 0; k < 7; ++k) step(24 + k, k);   // t = 24..30
}

// ---------------- main: fused a-prep + sij streaming, all 4 j per wave -----
// One wave per (z=b*6+i, 48-col strip, 32-row seg). Reads raw outputs +
// interleaved bc4/sjj4. Zero barriers, zero LDS arrays.
__global__ __launch_bounds__(64) void ncc_fused(
    const float* __restrict__ outs,
    const float* __restrict__ bc4, const float* __restrict__ sjj4,
    float* __restrict__ out)
{
    const int l  = threadIdx.x;
    const int x0 = 48 * blockIdx.x;
    const int y0 = 32 * blockIdx.y;
    const int z  = blockIdx.z;               // b*6 + i
    const int b  = z / 6;

    const float* acp  = outs + z * HW;       // raw a image
    const float* bcp  = bc4  + b * HW * 4;
    const float* sjp  = sjj4 + b * HW * 4;

    const int   gin  = x0 - 4 + l;
    const int   ginc = min(max(gin, 0), WW - 1);
    const float minA = (gin >= 0 && gin < WW) ? 1.f : 0.f;
    const int   gout  = x0 + l;
    const int   goutc = min(gout, WW - 1);
    const float outm  = (l < 48 && gout < WW) ? 1.f : 0.f;
    const int   a1 = ((l + 1) & 63) << 2, a2 = ((l + 2) & 63) << 2, a4 = ((l + 4) & 63) << 2;

    float araw[4], ha8[8], hii8[8], ring[4][8], VS[4];
    float VA = 0.f, VSII = 0.f, xs = 0.f;
    #pragma unroll
    for (int k = 0; k < 4; ++k) araw[k] = 0.f;
    #pragma unroll
    for (int k = 0; k < 8; ++k) { ha8[k] = 0.f; hii8[k] = 0.f; }
    #pragma unroll
    for (int j = 0; j < 4; ++j) {
        VS[j] = 0.f;
        #pragma unroll
        for (int k = 0; k < 8; ++k) ring[j][k] = 0.f;
    }

    auto step = [&](int t, int k) {
        const int r = y0 - 7 + t;
        float av = (r >= 0 && r < HH) ? acp[r * WW + ginc] * minA : 0.f;
        float han = win8(av, a1, a2, a4);
        VA += han - ha8[k]; ha8[k] = han;          // box rows c-3..c+4
        float aold = araw[k & 3];
        araw[k & 3] = av;
        if (t >= 8) {
            const int c  = r - 4;
            const int cc = min(max(c, 0), HH - 1);
            float acv = (c >= 0 && c < HH) ? (aold - VA * (1.f / 64.f)) * minA : 0.f;
            float4 bv = *(const float4*)&bcp[(cc * WW + ginc) * 4];
            float hii = win8(acv * acv, a1, a2, a4);
            VSII += hii - hii8[k]; hii8[k] = hii;  // box rows y-3..y+4
            float p[4] = {acv * bv.x, acv * bv.y, acv * bv.z, acv * bv.w};
            #pragma unroll
            for (int j = 0; j < 4; ++j) {
                float h = win8(p[j], a1, a2, a4);
                VS[j] += h - ring[j][k]; ring[j][k] = h;   // box rows c-7..c
            }
            if (t >= 15) {
                const int y = c - 4;                       // y in [y0, y0+31]
                float si = fmaxf(VSII, EPV);
                float4 sj = *(const float4*)&sjp[(y * WW + goutc) * 4];
                float mm = -1.f;
                mm = fmaxf(mm, VS[0] * __frsqrt_rn(fmaxf(si * sj.x, 1e-37f)));
                mm = fmaxf(mm, VS[1] * __frsqrt_rn(fmaxf(si * sj.y, 1e-37f)));
                mm = fmaxf(mm, VS[2] * __frsqrt_rn(fmaxf(si * sj.z, 1e-37f)));
                mm = fmaxf(mm, VS[3] * __frsqrt_rn(fmaxf(si * sj.w, 1e-37f)));
                xs += outm * (1.f - fminf(mm, 1.f));
            }
        }
    };

    for (int g = 0; g < 5; ++g) {
        #pragma unroll
        for (int k = 0; k < 8; ++k) step(g * 8 + k, k);
    }
    #pragma unroll
    for (int k = 0; k < 7; ++k) step(40 + k, k);   // t = 40..46

    #pragma unroll
    for (int off = 32; off > 0; off >>= 1) xs += __shfl_down(xs, off);
    if (l == 0) atomicAdd(&out[1 + z], xs * (1.f / (float)HW));
}

__global__ void finalize_kernel(float* __restrict__ out)
{
    if (threadIdx.x == 0) {
        float s = 0.f;
        #pragma unroll
        for (int z = 0; z < 24; ++z) s += out[1 + z];
        out[0] = s * (1.0f / 24.0f);
    }
}

extern "C" void kernel_launch(void* const* d_in, const int* in_sizes, int n_in,
                              void* d_out, int out_size, void* d_ws, size_t ws_size,
                              hipStream_t stream) {
    const float* outs = (const float*)d_in[0];   // (4,6,512,512)
    const float* labs = (const float*)d_in[1];   // (4,4,512,512)
    float* out = (float*)d_out;                  // 25 floats
    float* ws  = (float*)d_ws;

    float* bc4w  = ws;                 // 4*HW*4 floats = 16.8 MB
    float* sjj4w = ws + 16 * HW;       // 4*HW*4 floats

    hipMemsetAsync(d_out, 0, out_size * sizeof(float), stream);

    // prep_b: 11 strips x 32 segs of 16 rows x 4 batches, 1 wave each
    prep_b<<<dim3(11, 32, 4), 64, 0, stream>>>(labs, bc4w, sjj4w);
    // main: 11 strips x 16 segs of 32 rows x 24 (b,i), 1 wave each
    ncc_fused<<<dim3(11, 16, 24), 64, 0, stream>>>(outs, bc4w, sjj4w, out);
    finalize_kernel<<<1, 64, 0, stream>>>(out);
}

// Round 8
// 183.378 us; speedup vs baseline: 1.3356x; 1.3356x over previous
//
#include <hip/hip_runtime.h>

#define HH 512
#define WW 512
#define HW (HH*WW)
#define EPV 1e-20f

// Box window for center (y,x): rows y-3..y+4, cols x-3..x+4, zero-padded.
// Streaming cascade per wave (numerics verified absmax 0.0078 in R5-R7):
//   r = y0-7+t : raw row; ha = win8(raw); VA(ring8) = box rows c-3..c+4
//   t>=8      : c = r-4; acv = (raw(c) - VA/64) [masked outside image]
//               hii = win8(acv^2) -> VSII(ring8); hp_j = win8(acv*bc_j) -> VS_j
//   t>=15     : y = c-4; emit cc/max/X.
// R8: branch-free steady state + 8-deep register load FIFOs so loads for
// step t+8 issue at step t (the R7 runtime guards serialized every step).

__device__ __forceinline__ float bpf(int addr, float v) {
    return __int_as_float(__builtin_amdgcn_ds_bpermute(addr, __float_as_int(v)));
}

// h(l) = sum_{d=1..8} v(l+d); valid for lanes l <= 55 (wave64).
__device__ __forceinline__ float win8(float v, int a1, int a2, int a4) {
    float t = v + bpf(a1, v);
    t = t + bpf(a2, t);
    t = t + bpf(a4, t);
    return bpf(a1, t);
}

__device__ __forceinline__ int rclamp(int r) { return min(max(r, 0), HH - 1); }

// ---------------- prep_b: 4 label images per wave -> interleaved bc4, sjj4 --
// One wave per (b, 48-col strip, 16-row seg). Fully unrolled (31 const steps)
// so every guard folds; 8-deep FIFO on the 4 label-row streams.
__global__ __launch_bounds__(64) void prep_b(
    const float* __restrict__ labs,
    float* __restrict__ bc4, float* __restrict__ sjj4)
{
    const int l  = threadIdx.x;
    const int x0 = 48 * blockIdx.x;
    const int y0 = 16 * blockIdx.y;
    const int b  = blockIdx.z;

    const float* src0 = labs + (b * 4 + 0) * HW;
    const float* src1 = labs + (b * 4 + 1) * HW;
    const float* src2 = labs + (b * 4 + 2) * HW;
    const float* src3 = labs + (b * 4 + 3) * HW;

    const int   gin  = x0 - 4 + l;
    const int   ginc = min(max(gin, 0), WW - 1);
    const float minA = (gin >= 0 && gin < WW) ? 1.f : 0.f;
    const int   a1 = ((l + 1) & 63) << 2, a2 = ((l + 2) & 63) << 2, a4 = ((l + 4) & 63) << 2;
    const bool  st_c = (l >= 4 && l < 52 && gin < WW);
    const int   gout = x0 + l;
    const bool  st_s = (l < 48 && gout < WW);

    float pL0[8], pL1[8], pL2[8], pL3[8];
    #pragma unroll
    for (int k = 0; k < 8; ++k) {
        const int ro = rclamp(y0 - 7 + k) * WW + ginc;
        pL0[k] = src0[ro]; pL1[k] = src1[ro]; pL2[k] = src2[ro]; pL3[k] = src3[ro];
    }

    float araw[4][4], ha8[4][8], hii8[4][8], VA[4], VSII[4];
    #pragma unroll
    for (int j = 0; j < 4; ++j) {
        VA[j] = 0.f; VSII[j] = 0.f;
        #pragma unroll
        for (int k = 0; k < 4; ++k) araw[j][k] = 0.f;
        #pragma unroll
        for (int k = 0; k < 8; ++k) { ha8[j][k] = 0.f; hii8[j][k] = 0.f; }
    }

    #pragma unroll
    for (int t = 0; t < 31; ++t) {
        const int   k = t & 7;
        const int   r = y0 - 7 + t;
        const float rm = minA * ((r >= 0 && r < HH) ? 1.f : 0.f);
        float av[4] = { pL0[k] * rm, pL1[k] * rm, pL2[k] * rm, pL3[k] * rm };
        if (t < 23) {   // refill serves t+8 <= 30
            const int ro = rclamp(r + 8) * WW + ginc;
            pL0[k] = src0[ro]; pL1[k] = src1[ro]; pL2[k] = src2[ro]; pL3[k] = src3[ro];
        }
        const int   c  = r - 4;
        const float cm = minA * ((c >= 0 && c < HH) ? 1.f : 0.f);
        float acv[4];
        #pragma unroll
        for (int j = 0; j < 4; ++j) {
            float han = win8(av[j], a1, a2, a4);
            VA[j] += han - ha8[j][k]; ha8[j][k] = han;
            float aold = araw[j][t & 3];
            araw[j][t & 3] = av[j];
            acv[j] = (aold - VA[j] * (1.f / 64.f)) * cm;
        }
        if (t >= 11 && t < 27) {
            if (st_c)
                *(float4*)&bc4[((b * HW) + c * WW + gin) * 4] =
                    make_float4(acv[0], acv[1], acv[2], acv[3]);
        }
        if (t >= 8) {
            #pragma unroll
            for (int j = 0; j < 4; ++j) {
                float hin = win8(acv[j] * acv[j], a1, a2, a4);
                VSII[j] += hin - hii8[j][k]; hii8[j][k] = hin;
            }
            if (t >= 15) {
                if (st_s) {
                    const int y = c - 4;
                    *(float4*)&sjj4[((b * HW) + y * WW + gout) * 4] =
                        make_float4(fmaxf(VSII[0], EPV), fmaxf(VSII[1], EPV),
                                    fmaxf(VSII[2], EPV), fmaxf(VSII[3], EPV));
                }
            }
        }
    }
}

// ---------------- main: fused a-prep + sij streaming, all 4 j per wave -----
// One wave per (z=b*6+i, 48-col strip, 32-row seg). 8-deep FIFOs on the
// a-row, bc4-row and sjj4-row streams; warm-up/tail peeled with const t,
// steady loop (t=16..39) fully branch-free.
__global__ __launch_bounds__(64) void ncc_fused(
    const float* __restrict__ outs,
    const float* __restrict__ bc4, const float* __restrict__ sjj4,
    float* __restrict__ out)
{
    const int l  = threadIdx.x;
    const int x0 = 48 * blockIdx.x;
    const int y0 = 32 * blockIdx.y;
    const int z  = blockIdx.z;               // b*6 + i
    const int b  = z / 6;

    const float* acp = outs + z * HW;
    const float* bcp = bc4  + b * HW * 4;
    const float* sjp = sjj4 + b * HW * 4;

    const int   gin   = x0 - 4 + l;
    const int   ginc  = min(max(gin, 0), WW - 1);
    const float minA  = (gin >= 0 && gin < WW) ? 1.f : 0.f;
    const int   gout  = x0 + l;
    const int   goutc = min(gout, WW - 1);
    const float outm  = (l < 48 && gout < WW) ? 1.f : 0.f;
    const int   a1 = ((l + 1) & 63) << 2, a2 = ((l + 2) & 63) << 2, a4 = ((l + 4) & 63) << 2;

    float pAv[8]; float4 pBv[8], pSj[8];
    #pragma unroll
    for (int k = 0; k < 8; ++k) {
        pAv[k] = acp[rclamp(y0 - 7 + k) * WW + ginc];
        pBv[k] = make_float4(0.f, 0.f, 0.f, 0.f);
        pSj[k] = make_float4(0.f, 0.f, 0.f, 0.f);
    }

    float araw[4], ha8[8], hii8[8], ring[4][8], VS[4];
    float VA = 0.f, VSII = 0.f, xs = 0.f;
    #pragma unroll
    for (int k = 0; k < 4; ++k) araw[k] = 0.f;
    #pragma unroll
    for (int k = 0; k < 8; ++k) { ha8[k] = 0.f; hii8[k] = 0.f; }
    #pragma unroll
    for (int j = 0; j < 4; ++j) {
        VS[j] = 0.f;
        #pragma unroll
        for (int k = 0; k < 8; ++k) ring[j][k] = 0.f;
    }

    // FIFO phasing: pAv[k] holds row r(t)=y0-7+t; refill with r+8.
    // pBv[k] consumed at t holds bc4 row c(t)=y0-11+t; refill row r+4=c(t+8).
    // pSj[k] consumed at t holds sjj4 row y(t)=y0-15+t; refill row r=y(t+8).
    auto step = [&](int t, int k, bool doProd, bool doEmit, bool doRefill) {
        const int   r  = y0 - 7 + t;
        const float rm = minA * ((r >= 0 && r < HH) ? 1.f : 0.f);
        float  av = pAv[k] * rm;
        float4 bv = pBv[k];
        float4 sj = pSj[k];
        if (doRefill) {
            pAv[k] = acp[rclamp(r + 8) * WW + ginc];
            pBv[k] = *(const float4*)&bcp[(rclamp(r + 4) * WW + ginc) * 4];
            pSj[k] = *(const float4*)&sjp[(rclamp(r) * WW + goutc) * 4];
        }
        float han = win8(av, a1, a2, a4);
        VA += han - ha8[k]; ha8[k] = han;
        float aold = araw[k & 3];
        araw[k & 3] = av;
        if (doProd) {
            const int   c  = r - 4;
            const float cm = minA * ((c >= 0 && c < HH) ? 1.f : 0.f);
            float acv = (aold - VA * (1.f / 64.f)) * cm;
            float hii = win8(acv * acv, a1, a2, a4);
            VSII += hii - hii8[k]; hii8[k] = hii;
            float h0 = win8(acv * bv.x, a1, a2, a4);
            float h1 = win8(acv * bv.y, a1, a2, a4);
            float h2 = win8(acv * bv.z, a1, a2, a4);
            float h3 = win8(acv * bv.w, a1, a2, a4);
            VS[0] += h0 - ring[0][k]; ring[0][k] = h0;
            VS[1] += h1 - ring[1][k]; ring[1][k] = h1;
            VS[2] += h2 - ring[2][k]; ring[2][k] = h2;
            VS[3] += h3 - ring[3][k]; ring[3][k] = h3;
            if (doEmit) {
                float si = fmaxf(VSII, EPV);
                float mm =          VS[0] * __frsqrt_rn(fmaxf(si * sj.x, 1e-37f));
                mm = fmaxf(mm,      VS[1] * __frsqrt_rn(fmaxf(si * sj.y, 1e-37f)));
                mm = fmaxf(mm,      VS[2] * __frsqrt_rn(fmaxf(si * sj.z, 1e-37f)));
                mm = fmaxf(mm,      VS[3] * __frsqrt_rn(fmaxf(si * sj.w, 1e-37f)));
                xs += outm * (1.f - fminf(mm, 1.f));
            }
        }
    };

    // warm-up: const t, guards fold
    #pragma unroll
    for (int t = 0; t < 16; ++t) step(t, t & 7, t >= 8, t >= 15, true);
    // steady: branch-free body, loads always 8 steps ahead
    for (int g = 2; g < 5; ++g) {
        #pragma unroll
        for (int k = 0; k < 8; ++k) step(g * 8 + k, k, true, true, true);
    }
    // tail: const t, no refills
    #pragma unroll
    for (int t = 40; t < 47; ++t) step(t, t & 7, true, true, false);

    #pragma unroll
    for (int off = 32; off > 0; off >>= 1) xs += __shfl_down(xs, off);
    if (l == 0) atomicAdd(&out[1 + z], xs * (1.f / (float)HW));
}

__global__ void finalize_kernel(float* __restrict__ out)
{
    if (threadIdx.x == 0) {
        float s = 0.f;
        #pragma unroll
        for (int z = 0; z < 24; ++z) s += out[1 + z];
        out[0] = s * (1.0f / 24.0f);
    }
}

extern "C" void kernel_launch(void* const* d_in, const int* in_sizes, int n_in,
                              void* d_out, int out_size, void* d_ws, size_t ws_size,
                              hipStream_t stream) {
    const float* outs = (const float*)d_in[0];   // (4,6,512,512)
    const float* labs = (const float*)d_in[1];   // (4,4,512,512)
    float* out = (float*)d_out;                  // 25 floats
    float* ws  = (float*)d_ws;

    float* bc4w  = ws;                 // 4*HW*4 floats = 16.8 MB
    float* sjj4w = ws + 16 * HW;       // 4*HW*4 floats

    hipMemsetAsync(d_out, 0, out_size * sizeof(float), stream);

    // prep_b: 11 strips x 32 segs of 16 rows x 4 batches, 1 wave each
    prep_b<<<dim3(11, 32, 4), 64, 0, stream>>>(labs, bc4w, sjj4w);
    // main: 11 strips x 16 segs of 32 rows x 24 (b,i), 1 wave each
    ncc_fused<<<dim3(11, 16, 24), 64, 0, stream>>>(outs, bc4w, sjj4w, out);
    finalize_kernel<<<1, 64, 0, stream>>>(out);
}

// Round 9
// 177.660 us; speedup vs baseline: 1.3786x; 1.0322x over previous
//
#include <hip/hip_runtime.h>

#define HH 512
#define WW 512
#define HW (HH*WW)
#define EPV 1e-20f

// Box window for center (y,x): rows y-3..y+4, cols x-3..x+4, zero-padded.
// R9: 4 cols/lane (float4). Horizontal windows via prefix/suffix exchange:
//   winC(u) = sum_{d=-3..+4} v(u+d)  (centered, 7 bp)  -- mean window
//   winR(u) = sum_{d=1..8}  v(u+d)  (right,    5 bp)  -- h for output col x0+u
// Vertical = register rings (depth 8), sliding sums, as verified R5-R8.
// Unified workspace: plane z<24 = a-images (ac, sii), z>=24 = labels (bc, sjj).

__device__ __forceinline__ float bpl(int addr, float v) {
    return __int_as_float(__builtin_amdgcn_ds_bpermute(addr, __float_as_int(v)));
}
__device__ __forceinline__ int rcl(int r) { return min(max(r, 0), HH - 1); }

// centered window over strip cols u=4*lane+e
__device__ __forceinline__ float4 winC(float4 v, int aL1, int aR1) {
    float pre2 = v.x + v.y, pre3 = pre2 + v.z, g = pre3 + v.w;
    float suf2 = v.z + v.w, suf3 = v.y + suf2;
    float Ls1 = bpl(aL1, v.w), Ls2 = bpl(aL1, suf2), Ls3 = bpl(aL1, suf3);
    float Rp1 = bpl(aR1, v.x), Rp2 = bpl(aR1, pre2), Rp3 = bpl(aR1, pre3);
    float Rg  = bpl(aR1, g);
    return make_float4(Ls3 + g + Rp1, Ls2 + g + Rp2, Ls1 + g + Rp3, g + Rg);
}
// right-leaning window (serves output col x0+u)
__device__ __forceinline__ float4 winR(float4 v, int aR1, int aR2) {
    float pre2 = v.x + v.y, pre3 = pre2 + v.z, g = pre3 + v.w;
    float suf2 = v.z + v.w, suf3 = v.y + suf2;
    float G1 = bpl(aR1, g);
    float P1 = bpl(aR2, v.x), P2 = bpl(aR2, pre2), P3 = bpl(aR2, pre3);
    float G2 = bpl(aR2, g);
    return make_float4(suf3 + G1 + P1, suf2 + G1 + P2, v.w + G1 + P3, G1 + G2);
}

// ---------------- prep: raw image -> centered (ac) + variance box (sii) ----
// One wave per (z, strip, 32-row seg). Strips x0 = {0,232,468}.
__global__ __launch_bounds__(64) void prep_f4(
    const float* __restrict__ outs, const float* __restrict__ labs,
    float* __restrict__ ac, float* __restrict__ sii)
{
    const int l  = threadIdx.x;
    const int s  = blockIdx.x;
    const int x0 = (s == 0) ? 0 : (s == 1 ? 232 : 468);
    const int y0 = 32 * blockIdx.y;
    const int z  = blockIdx.z;

    const float* src = (z < 24) ? outs + z * HW : labs + (z - 24) * HW;
    float* acd = ac  + z * HW;
    float* sid = sii + z * HW;

    const int   bcol0 = x0 - 4 + 4 * l;
    const int   bcol  = min(max(bcol0, 0), WW - 4);
    const float cmask = (bcol0 >= 0 && bcol0 <= WW - 4) ? 1.f : 0.f;
    const int   ocol0 = x0 + 4 * l;
    const int   aL1 = ((l - 1) & 63) << 2;
    const int   aR1 = ((l + 1) & 63) << 2;
    const int   aR2 = ((l + 2) & 63) << 2;
    // ac store: u in [4,243] -> l in [1,60]; col base in [0,508]
    const bool stA = (l >= 1 && l <= 60 && bcol0 >= 0 && bcol0 <= WW - 4);
    // sii store: u in [us,239]; us=0 for x0==0 (left zeros valid) else 4
    const bool stS = (l >= ((x0 == 0) ? 0 : 1) && l <= 59 && ocol0 <= WW - 4);

    float4 fifo[2];
    fifo[0] = *(const float4*)&src[rcl(y0 - 7) * WW + bcol];
    fifo[1] = *(const float4*)&src[rcl(y0 - 6) * WW + bcol];

    float4 araw[4], haR[8], hsR[8];
    float4 VA = make_float4(0,0,0,0), VS = make_float4(0,0,0,0);
    #pragma unroll
    for (int k = 0; k < 4; ++k) araw[k] = make_float4(0,0,0,0);
    #pragma unroll
    for (int k = 0; k < 8; ++k) { haR[k] = make_float4(0,0,0,0); hsR[k] = make_float4(0,0,0,0); }

    auto step = [&](int t) {
        const int   k  = t & 7;
        const int   r  = y0 - 7 + t;
        const float rm = (r >= 0 && r < HH) ? cmask : 0.f;
        float4 raw = fifo[t & 1];
        float4 av  = make_float4(raw.x*rm, raw.y*rm, raw.z*rm, raw.w*rm);
        if (t <= 44) fifo[t & 1] = *(const float4*)&src[rcl(r + 2) * WW + bcol];

        float4 h = winC(av, aL1, aR1);
        VA.x += h.x - haR[k].x; VA.y += h.y - haR[k].y;
        VA.z += h.z - haR[k].z; VA.w += h.w - haR[k].w;
        haR[k] = h;

        float4 aold = araw[t & 3]; araw[t & 3] = av;   // row c = r-4
        const int   c  = r - 4;
        const float cm = (c >= 0 && c < HH) ? cmask : 0.f;
        float4 acv = make_float4((aold.x - VA.x*(1.f/64.f))*cm,
                                 (aold.y - VA.y*(1.f/64.f))*cm,
                                 (aold.z - VA.z*(1.f/64.f))*cm,
                                 (aold.w - VA.w*(1.f/64.f))*cm);
        if (t >= 11 && t <= 42) {
            if (stA) *(float4*)&acd[c * WW + bcol0] = acv;
        }
        float4 sq = make_float4(acv.x*acv.x, acv.y*acv.y, acv.z*acv.z, acv.w*acv.w);
        float4 h2 = winR(sq, aR1, aR2);
        VS.x += h2.x - hsR[k].x; VS.y += h2.y - hsR[k].y;
        VS.z += h2.z - hsR[k].z; VS.w += h2.w - hsR[k].w;
        hsR[k] = h2;
        if (t >= 15) {
            const int y = c - 4;                        // y in [y0, y0+31]
            if (stS) *(float4*)&sid[y * WW + ocol0] =
                make_float4(fmaxf(VS.x, EPV), fmaxf(VS.y, EPV),
                            fmaxf(VS.z, EPV), fmaxf(VS.w, EPV));
        }
    };
    #pragma unroll
    for (int t = 0; t < 47; ++t) step(t);
}

// ---------------- main: product boxes, all 4 j per wave --------------------
// One wave per (z=b*6+i, strip x0={0,240,480}, 16-row seg). 23 steps.
__global__ __launch_bounds__(64, 2) void ncc_f4(
    const float* __restrict__ ac, const float* __restrict__ sii,
    float* __restrict__ out)
{
    const int l  = threadIdx.x;
    const int x0 = 240 * blockIdx.x;
    const int y0 = 16 * blockIdx.y;
    const int z  = blockIdx.z;               // b*6 + i
    const int b  = z / 6;

    const float* acp = ac + z * HW;
    const float* sip = sii + z * HW;
    const float* bcp[4]; const float* sjp[4];
    #pragma unroll
    for (int j = 0; j < 4; ++j) {
        bcp[j] = ac  + (24 + b * 4 + j) * HW;
        sjp[j] = sii + (24 + b * 4 + j) * HW;
    }

    const int   bcol0 = x0 - 4 + 4 * l;
    const int   bcol  = min(max(bcol0, 0), WW - 4);
    const float cmask = (bcol0 >= 0 && bcol0 <= WW - 4) ? 1.f : 0.f;
    const int   ocol0 = x0 + 4 * l;
    const int   ocol  = min(ocol0, WW - 4);
    const float om    = (l <= 59 && ocol0 <= WW - 4) ? 1.f : 0.f;
    const int   aR1 = ((l + 1) & 63) << 2;
    const int   aR2 = ((l + 2) & 63) << 2;

    float4 fa[2], fb[4][2];
    {
        const int r0 = rcl(y0 - 3), r1 = rcl(y0 - 2);
        fa[0] = *(const float4*)&acp[r0 * WW + bcol];
        fa[1] = *(const float4*)&acp[r1 * WW + bcol];
        #pragma unroll
        for (int j = 0; j < 4; ++j) {
            fb[j][0] = *(const float4*)&bcp[j][r0 * WW + bcol];
            fb[j][1] = *(const float4*)&bcp[j][r1 * WW + bcol];
        }
    }

    float4 ring[4][8], VS[4];
    #pragma unroll
    for (int j = 0; j < 4; ++j) {
        VS[j] = make_float4(0,0,0,0);
        #pragma unroll
        for (int k = 0; k < 8; ++k) ring[j][k] = make_float4(0,0,0,0);
    }
    float4 xs = make_float4(0,0,0,0);
    float4 psi = make_float4(0,0,0,0), psj[4];
    #pragma unroll
    for (int j = 0; j < 4; ++j) psj[j] = make_float4(0,0,0,0);

    auto step = [&](int t) {
        const int   k  = t & 7;
        const int   c  = y0 - 3 + t;
        const float rm = (c >= 0 && c < HH) ? cmask : 0.f;
        float4 av = fa[t & 1];
        av = make_float4(av.x*rm, av.y*rm, av.z*rm, av.w*rm);
        float4 bv0 = fb[0][t & 1], bv1 = fb[1][t & 1];
        float4 bv2 = fb[2][t & 1], bv3 = fb[3][t & 1];
        if (t <= 20) {
            const int rn = rcl(c + 2);
            fa[t & 1] = *(const float4*)&acp[rn * WW + bcol];
            #pragma unroll
            for (int j = 0; j < 4; ++j)
                fb[j][t & 1] = *(const float4*)&bcp[j][rn * WW + bcol];
        }
        // prefetch sii/sjj for NEXT step's emit (row y(t+1) = y0+t-6)
        if (t >= 6 && t <= 21) {
            const int yn = y0 + t - 6;
            psi = *(const float4*)&sip[yn * WW + ocol];
            #pragma unroll
            for (int j = 0; j < 4; ++j)
                psj[j] = *(const float4*)&sjp[j][yn * WW + ocol];
        }
        float4 h;
        h = winR(make_float4(av.x*bv0.x, av.y*bv0.y, av.z*bv0.z, av.w*bv0.w), aR1, aR2);
        VS[0].x += h.x - ring[0][k].x; VS[0].y += h.y - ring[0][k].y;
        VS[0].z += h.z - ring[0][k].z; VS[0].w += h.w - ring[0][k].w; ring[0][k] = h;
        h = winR(make_float4(av.x*bv1.x, av.y*bv1.y, av.z*bv1.z, av.w*bv1.w), aR1, aR2);
        VS[1].x += h.x - ring[1][k].x; VS[1].y += h.y - ring[1][k].y;
        VS[1].z += h.z - ring[1][k].z; VS[1].w += h.w - ring[1][k].w; ring[1][k] = h;
        h = winR(make_float4(av.x*bv2.x, av.y*bv2.y, av.z*bv2.z, av.w*bv2.w), aR1, aR2);
        VS[2].x += h.x - ring[2][k].x; VS[2].y += h.y - ring[2][k].y;
        VS[2].z += h.z - ring[2][k].z; VS[2].w += h.w - ring[2][k].w; ring[2][k] = h;
        h = winR(make_float4(av.x*bv3.x, av.y*bv3.y, av.z*bv3.z, av.w*bv3.w), aR1, aR2);
        VS[3].x += h.x - ring[3][k].x; VS[3].y += h.y - ring[3][k].y;
        VS[3].z += h.z - ring[3][k].z; VS[3].w += h.w - ring[3][k].w; ring[3][k] = h;

        if (t >= 7) {
            float4 si = psi;
            float mmx = -1.f, mmy = -1.f, mmz = -1.f, mmw = -1.f;
            #pragma unroll
            for (int j = 0; j < 4; ++j) {
                float4 sj = psj[j];
                mmx = fmaxf(mmx, VS[j].x * __frsqrt_rn(fmaxf(si.x * sj.x, 1e-37f)));
                mmy = fmaxf(mmy, VS[j].y * __frsqrt_rn(fmaxf(si.y * sj.y, 1e-37f)));
                mmz = fmaxf(mmz, VS[j].z * __frsqrt_rn(fmaxf(si.z * sj.z, 1e-37f)));
                mmw = fmaxf(mmw, VS[j].w * __frsqrt_rn(fmaxf(si.w * sj.w, 1e-37f)));
            }
            xs.x += om * (1.f - fminf(mmx, 1.f));
            xs.y += om * (1.f - fminf(mmy, 1.f));
            xs.z += om * (1.f - fminf(mmz, 1.f));
            xs.w += om * (1.f - fminf(mmw, 1.f));
        }
    };
    #pragma unroll
    for (int t = 0; t < 23; ++t) step(t);

    float xt = xs.x + xs.y + xs.z + xs.w;
    #pragma unroll
    for (int off = 32; off > 0; off >>= 1) xt += __shfl_down(xt, off);
    if (l == 0) {
        atomicAdd(&out[1 + z], xt * (1.f / (float)HW));
        atomicAdd(&out[0],     xt * (1.f / (24.f * (float)HW)));
    }
}

extern "C" void kernel_launch(void* const* d_in, const int* in_sizes, int n_in,
                              void* d_out, int out_size, void* d_ws, size_t ws_size,
                              hipStream_t stream) {
    const float* outs = (const float*)d_in[0];   // (4,6,512,512)
    const float* labs = (const float*)d_in[1];   // (4,4,512,512)
    float* out = (float*)d_out;                  // 25 floats
    float* ws  = (float*)d_ws;

    float* acw  = ws;                 // 40*HW (a:0..23, b:24..39)
    float* siiw = ws + 40 * HW;       // 40*HW

    hipMemsetAsync(d_out, 0, out_size * sizeof(float), stream);

    // prep: 3 strips x 16 segs(32 rows) x 40 images
    prep_f4<<<dim3(3, 16, 40), 64, 0, stream>>>(outs, labs, acw, siiw);
    // main: 3 strips x 32 segs(16 rows) x 24 (b,i)
    ncc_f4<<<dim3(3, 32, 24), 64, 0, stream>>>(acw, siiw, out);
}